// Round 11
// baseline (27960.312 us; speedup 1.0000x reference)
//
#include <hip/hip_runtime.h>
#include <hip/hip_bf16.h>
#include <cstddef>
#include <cstdint>

// ---------------------------------------------------------------------------
// LSTM_intensity: persistent kernel, plain launch + hand-rolled device-scope
// atomic grid barrier. Spin is BOUNDED: if a barrier can't complete (blocks
// not co-resident), give up after ~200K polls -> bench fails fast with large
// absmax instead of hanging the container (r10 diagnostic).
// 256 blocks x 256 threads. Block = 32 batch rows x 16 h-cols; wave w = gate w.
// Weights (96 VGPR/lane) and c-state (2 f32/lane) live in registers across all
// 512 steps; h exchanged via global + barrier.
// Co-residency: LDS 73.7KB/block -> <=2 blocks/CU -> 512 slots >= 256 blocks.
// ---------------------------------------------------------------------------

#define T_STEPS 512
#define BATCH 256
#define ISZ 256
#define HID 512
#define KTOT 768          // 256 (x) + 512 (h)
#define KT_STEPS 24       // 768 / 32
#define AP 776            // A-tile LDS row stride in halfs (768 + 8 pad)
#define NBLK 256
#define SPIN_CAP 200000   // polls; ~64cyc each -> few ms max per barrier

typedef _Float16 half8 __attribute__((ext_vector_type(8)));
typedef float f32x4 __attribute__((ext_vector_type(4)));

// ---- workspace layout (bytes) ----
#define WS_XH    0            // 512*256*256 halfs = 67,108,864 B
#define WS_WP    67108864     // 768*2048 halfs    =  3,145,728 B
#define WS_HB0   70254592     // 131072 halfs      =    262,144 B
#define WS_HB1   70516736     // 131072 halfs      =    262,144 B
#define WS_CNT   70778880     // 1 u32 barrier counter
// total ~70.8 MB

// Convert X fp32 -> fp16 (same [T][B][I] row-major layout)
__global__ void k_convX(const float* __restrict__ X, _Float16* __restrict__ Xh) {
    const size_t n4 = (size_t)T_STEPS * BATCH * ISZ / 4;
    for (size_t i = (size_t)blockIdx.x * blockDim.x + threadIdx.x; i < n4;
         i += (size_t)gridDim.x * blockDim.x) {
        float4 v = ((const float4*)X)[i];
        _Float16 h4[4] = {(_Float16)v.x, (_Float16)v.y, (_Float16)v.z, (_Float16)v.w};
        *(uint2*)(Xh + i * 4) = *(const uint2*)h4;
    }
}

// Pack [W_ih | W_hh] into MFMA-B-fragment-linear fp16 layout.
// Element at tile*512 + lane*8 + i  <->  B[k][n],
//   k = kt*32 + (lane>>4)*8 + i, n = nt*16 + (lane&15), tile = nt*24 + kt.
__global__ void k_pack(const float* __restrict__ Wih, const float* __restrict__ Whh,
                       _Float16* __restrict__ Wp) {
    int idx = blockIdx.x * 256 + threadIdx.x;
    if (idx >= KTOT * 2048) return;
    int i    = idx & 7;
    int lane = (idx >> 3) & 63;
    int tile = idx >> 9;
    int kt = tile % KT_STEPS;
    int nt = tile / KT_STEPS;
    int n = nt * 16 + (lane & 15);
    int k = kt * 32 + (lane >> 4) * 8 + i;
    float v = (k < ISZ) ? Wih[n * ISZ + k] : Whh[n * HID + (k - ISZ)];
    Wp[idx] = (_Float16)v;
}

// h0 fp32 -> fp16, zero barrier counter (d_ws is re-poisoned before each call!)
__global__ void k_inith(const float* __restrict__ h0, _Float16* __restrict__ hb,
                        unsigned int* __restrict__ cnt) {
    int idx = blockIdx.x * 256 + threadIdx.x;   // 131072 threads
    if (threadIdx.x == 0) *cnt = 0u;            // every block writes 0 (race-free)
    hb[idx] = (_Float16)h0[idx];
}

__device__ __forceinline__ float sigm(float x) { return 1.f / (1.f + __expf(-x)); }
__device__ __forceinline__ float tanh_fast(float x) { return 2.f / (1.f + __expf(-2.f * x)) - 1.f; }

// Device-scope grid barrier, monotone target (no reset race). BOUNDED spin:
// on pathological non-residency we give up (results corrupt -> absmax flags
// it) instead of hanging the container.
__device__ __forceinline__ void grid_barrier(unsigned int* cnt, unsigned int target) {
    __threadfence();
    __syncthreads();
    if (threadIdx.x == 0) {
        __hip_atomic_fetch_add(cnt, 1u, __ATOMIC_RELEASE, __HIP_MEMORY_SCOPE_AGENT);
        unsigned int polls = 0;
        while (__hip_atomic_load(cnt, __ATOMIC_ACQUIRE, __HIP_MEMORY_SCOPE_AGENT) < target
               && ++polls < SPIN_CAP)
            __builtin_amdgcn_s_sleep(1);
    }
    __syncthreads();
    __threadfence();
}

// Persistent LSTM scan. 256 blocks x 256 threads.
// blk: bt = blk>>5 (8 row-tiles of 32), jt = blk&31 (32 col-tiles of 16 h-cols).
__global__ __launch_bounds__(256, 1) void k_lstm(
    const _Float16* __restrict__ Xh, const _Float16* __restrict__ Wp,
    const float* __restrict__ bih, const float* __restrict__ bhh,
    _Float16* hb0, _Float16* hb1,
    const float* __restrict__ c0,
    const float* __restrict__ W1, const float* __restrict__ b1,
    const float* __restrict__ W2, const float* __restrict__ b2,
    float* __restrict__ out, unsigned int* __restrict__ cnt)
{
    __shared__ _Float16 A[32 * AP];     // [32 rows][768 + pad] staged x_t | h
    __shared__ float gbuf[32 * 68];     // gate exchange: [row][gate*16+col], pad 4
    __shared__ float w1s[5 * HID];      // W1 copy (jt==0 blocks only)
    __shared__ float yp[32 * 8 * 5];    // head partials

    const int tid = threadIdx.x;
    const int blk = blockIdx.x;
    const int bt = blk >> 5, jt = blk & 31;
    const int b0 = bt * 32, j0 = jt * 16;
    const int wave = tid >> 6, lane = tid & 63;   // wave == gate index

    // ---- one-time: B fragments (this wave's gate panel, 16 cols x K=768) ----
    const int nt = wave * 32 + jt;                // N-tile in the 2048-col gate mat
    half8 bfrag[KT_STEPS];                        // 96 VGPRs
    #pragma unroll
    for (int kt = 0; kt < KT_STEPS; ++kt)
        bfrag[kt] = *(const half8*)(Wp + ((size_t)(nt * KT_STEPS + kt) << 9) + lane * 8);

    // ---- one-time: epilogue constants; cells (tid*2, tid*2+1) of 32x16 tile ----
    const int erow = (tid * 2) >> 4;
    const int ecol = (tid * 2) & 15;
    float bias[2][4];
    float creg[2];
    #pragma unroll
    for (int e = 0; e < 2; ++e) {
        int j = j0 + ecol + e;
        #pragma unroll
        for (int g = 0; g < 4; ++g)
            bias[e][g] = bih[g * HID + j] + bhh[g * HID + j];
        creg[e] = c0[(size_t)(b0 + erow) * HID + j];
    }

    // ---- one-time: head constants (jt==0 blocks) ----
    float w2r[5] = {0,0,0,0,0}, b1r[5] = {0,0,0,0,0}, b2r = 0.f;
    if (jt == 0) {
        for (int i = tid; i < 5 * HID; i += 256) w1s[i] = W1[i];
        #pragma unroll
        for (int m = 0; m < 5; ++m) { w2r[m] = W2[m]; b1r[m] = b1[m]; }
        b2r = b2[0];
    }

    // Iteration t: stages state s_t (s_0 = h0) from buf[t&1], computes head
    // y_{t-1} from it (t>0), runs step t -> s_{t+1} into buf[(t+1)&1].
    // Iteration T_STEPS is head-only (y_511).
    for (int t = 0; t <= T_STEPS; ++t) {
        const _Float16* hprev = (t & 1) ? hb1 : hb0;
        _Float16*       hnext = (t & 1) ? hb0 : hb1;

        // ---- stage A-tile: x_t (k 0..255) + s_t (k 256..767) ----
        #pragma unroll
        for (int it = 0; it < 12; ++it) {
            int cid = tid + it * 256;
            if (cid < 1024) {
                if (t < T_STEPS) {
                    int r = cid >> 5, kh = (cid & 31) * 8;
                    *(uint4*)&A[r * AP + kh] =
                        *(const uint4*)(Xh + ((size_t)t * BATCH + b0 + r) * ISZ + kh);
                }
            } else {
                int c2 = cid - 1024;
                int r = c2 >> 6, kh = (c2 & 63) * 8;
                *(uint4*)&A[r * AP + ISZ + kh] =
                    *(const uint4*)(hprev + (size_t)(b0 + r) * HID + kh);
            }
        }
        __syncthreads();

        // ---- head phase 1: partials of s_t @ W1.T (jt==0 blocks) ----
        if (jt == 0 && t > 0) {
            int row = tid >> 3, seg = tid & 7;
            float p[5] = {0.f, 0.f, 0.f, 0.f, 0.f};
            int kb = seg * 64;
            for (int k = kb; k < kb + 64; ++k) {
                float hv = (float)A[row * AP + ISZ + k];
                #pragma unroll
                for (int m = 0; m < 5; ++m) p[m] += hv * w1s[m * HID + k];
            }
            #pragma unroll
            for (int m = 0; m < 5; ++m) yp[(row * 8 + seg) * 5 + m] = p[m];
        }

        if (t < T_STEPS) {
            // ---- MFMA: this wave's gate, 32 rows x 16 cols, K=768 ----
            f32x4 acc0 = {0.f, 0.f, 0.f, 0.f}, acc1 = {0.f, 0.f, 0.f, 0.f};
            const int ar0 = (lane & 15) * AP + (lane >> 4) * 8;
            #pragma unroll
            for (int kt = 0; kt < KT_STEPS; ++kt) {
                half8 a0 = *(const half8*)&A[ar0 + kt * 32];
                half8 a1 = *(const half8*)&A[ar0 + 16 * AP + kt * 32];
                acc0 = __builtin_amdgcn_mfma_f32_16x16x32_f16(a0, bfrag[kt], acc0, 0, 0, 0);
                acc1 = __builtin_amdgcn_mfma_f32_16x16x32_f16(a1, bfrag[kt], acc1, 0, 0, 0);
            }
            // C-tile layout: col = lane&15, row = (lane>>4)*4 + i  [m89]
            {
                int col = lane & 15, r4 = (lane >> 4) * 4;
                #pragma unroll
                for (int i = 0; i < 4; ++i) {
                    gbuf[(r4 + i) * 68 + wave * 16 + col]      = acc0[i];
                    gbuf[(16 + r4 + i) * 68 + wave * 16 + col] = acc1[i];
                }
            }
        }
        __syncthreads();

        // ---- head phase 2 -> out[t-1] ----
        if (jt == 0 && t > 0 && tid < 32) {
            float z = b2r;
            #pragma unroll
            for (int m = 0; m < 5; ++m) {
                float am = b1r[m];
                for (int s = 0; s < 8; ++s) am += yp[(tid * 8 + s) * 5 + m];
                z += am * w2r[m];
            }
            out[(size_t)(t - 1) * BATCH + b0 + tid] = z > 0.f ? z : (__expf(z) - 1.f);
        }

        if (t < T_STEPS) {
            // ---- epilogue: gates -> c (regs), h -> hnext ----
            union { _Float16 h[2]; uint32_t u; } hu;
            #pragma unroll
            for (int e = 0; e < 2; ++e) {
                int col = ecol + e;
                float gi = gbuf[erow * 68 + 0 * 16 + col] + bias[e][0];
                float gf = gbuf[erow * 68 + 1 * 16 + col] + bias[e][1];
                float gg = gbuf[erow * 68 + 2 * 16 + col] + bias[e][2];
                float go = gbuf[erow * 68 + 3 * 16 + col] + bias[e][3];
                float si = sigm(gi), sf = sigm(gf), tg = tanh_fast(gg), so = sigm(go);
                float cn = sf * creg[e] + si * tg;
                creg[e] = cn;
                hu.h[e] = (_Float16)(so * tanh_fast(cn));
            }
            *(uint32_t*)(hnext + (size_t)(b0 + erow) * HID + j0 + ecol) = hu.u;
            grid_barrier(cnt, (unsigned int)(t + 1) * NBLK);
        }
    }
}

extern "C" void kernel_launch(void* const* d_in, const int* in_sizes, int n_in,
                              void* d_out, int out_size, void* d_ws, size_t ws_size,
                              hipStream_t stream) {
    const float* X   = (const float*)d_in[0];
    const float* h0  = (const float*)d_in[1];
    const float* c0  = (const float*)d_in[2];
    const float* Wih = (const float*)d_in[3];
    const float* Whh = (const float*)d_in[4];
    const float* bih = (const float*)d_in[5];
    const float* bhh = (const float*)d_in[6];
    const float* W1  = (const float*)d_in[7];
    const float* b1  = (const float*)d_in[8];
    const float* W2  = (const float*)d_in[9];
    const float* b2  = (const float*)d_in[10];
    float* out = (float*)d_out;

    char* ws = (char*)d_ws;
    _Float16* Xh  = (_Float16*)(ws + WS_XH);
    _Float16* Wp  = (_Float16*)(ws + WS_WP);
    _Float16* hb0 = (_Float16*)(ws + WS_HB0);
    _Float16* hb1 = (_Float16*)(ws + WS_HB1);
    unsigned int* cnt = (unsigned int*)(ws + WS_CNT);

    k_convX<<<2048, 256, 0, stream>>>(X, Xh);
    k_pack<<<(KTOT * 2048 + 255) / 256, 256, 0, stream>>>(Wih, Whh, Wp);
    k_inith<<<512, 256, 0, stream>>>(h0, hb0, cnt);

    k_lstm<<<NBLK, 256, 0, stream>>>(Xh, Wp, bih, bhh, hb0, hb1, c0,
                                     W1, b1, W2, b2, out, cnt);
}